// Round 11
// baseline (42.491 us; speedup 1.0000x reference)
//
#include <hip/hip_runtime.h>

// WOMD post-processing v11: 8 agents per wave (8 lanes/agent, 4 modes/lane),
// 512 waves total (half of v10, quarter of v2). Zero LDS. Continues the
// empirically-winning axis: fewer waves at slightly longer per-wave stream.
// All discrete comparisons (argmax ties, within-threshold) keep the exact
// form of the passing v10 kernel; sel[]/pt[] are literal-indexed only.

#define NSC 64
#define NAG 64
#define NJF 32
#define NSTEP 80
#define KP 6
#define TOUT 16

struct F3 { float x, y, z; };

__global__ __launch_bounds__(64)
void womd_pp11(const float* __restrict__ ag_type,
               const float* __restrict__ trajs,
               const float* __restrict__ scores,
               float* __restrict__ out)
{
    const int tid = threadIdx.x;
    const int g   = tid >> 3;              // agent slot 0..7
    const int o   = tid & 7;               // lane offset within 8-group
    const int ga  = blockIdx.x * 8 + g;    // global agent 0..4095
    const int s   = ga >> 6;               // scene
    const int a   = ga & 63;               // agent

    // lane owns modes o, o+8, o+16, o+24
    // ---- loads ----
    const float* sp = scores + (size_t)s * NJF * NAG + a;
    float raw0 = sp[(size_t)(o)      * NAG];
    float raw1 = sp[(size_t)(o + 8)  * NAG];
    float raw2 = sp[(size_t)(o + 16) * NAG];
    float raw3 = sp[(size_t)(o + 24) * NAG];

    const float* tb = trajs + (size_t)s * NJF * NAG * NSTEP * 3;  // scene base
    #define EOFF(j) ((((size_t)(j) * NAG + a) * NSTEP + (NSTEP - 1)) * 3)
    float2 p0 = *(const float2*)(tb + EOFF(o));
    float2 p1 = *(const float2*)(tb + EOFF(o + 8));
    float2 p2 = *(const float2*)(tb + EOFF(o + 16));
    float2 p3 = *(const float2*)(tb + EOFF(o + 24));

    F3 atv = *(const F3*)(ag_type + (size_t)(s * NAG + a) * 3);
    const float thresh = atv.x * 2.5f + atv.y * 1.0f + atv.z * 2.0f;

    // ---- softmax over 32 modes (serial-4 + 8-lane butterfly) ----
    float mx = fmaxf(fmaxf(raw0, raw1), fmaxf(raw2, raw3));
    #pragma unroll
    for (int off = 4; off > 0; off >>= 1)
        mx = fmaxf(mx, __shfl_xor(mx, off, 8));
    float ev0 = expf(raw0 - mx);
    float ev1 = expf(raw1 - mx);
    float ev2 = expf(raw2 - mx);
    float ev3 = expf(raw3 - mx);
    float sum = ev0 + ev1 + ev2 + ev3;
    #pragma unroll
    for (int off = 4; off > 0; off >>= 1)
        sum += __shfl_xor(sum, off, 8);
    float sm0 = ev0 / sum, sm1 = ev1 / sum, sm2 = ev2 / sum, sm3 = ev3 / sum;

    // ---- MTR NMS: 6 picks ----
    int   sel[KP];
    float skp[KP], sxp[KP], syp[KP];
    float ls0 = sm0, ls1 = sm1, ls2 = sm2, ls3 = sm3;
    #pragma unroll
    for (int k = 0; k < KP; ++k) {
        // per-lane scan in ascending mode order (strict > keeps lower mode)
        float v = ls0; int idx = o;
        if (ls1 > v) { v = ls1; idx = o + 8; }
        if (ls2 > v) { v = ls2; idx = o + 16; }
        if (ls3 > v) { v = ls3; idx = o + 24; }
        // 3-level (value, index) butterfly, first-index tie-break
        #pragma unroll
        for (int off = 4; off > 0; off >>= 1) {
            float ov = __shfl_xor(v, off, 8);
            int   oi = __shfl_xor(idx, off, 8);
            if (ov > v || (ov == v && oi < idx)) { v = ov; idx = oi; }
        }
        sel[k] = idx;                      // uniform within the 8-group

        // pick endpoint + score: select by reg (idx>>3), shuffle from lane idx&7
        int reg = idx >> 3;
        float sxv = (reg == 0) ? p0.x : (reg == 1) ? p1.x : (reg == 2) ? p2.x : p3.x;
        float syv = (reg == 0) ? p0.y : (reg == 1) ? p1.y : (reg == 2) ? p2.y : p3.y;
        float skv = (reg == 0) ? sm0  : (reg == 1) ? sm1  : (reg == 2) ? sm2  : sm3;
        float px = __shfl(sxv, idx & 7, 8);
        float py = __shfl(syv, idx & 7, 8);
        float pk = __shfl(skv, idx & 7, 8);
        sxp[k] = px;  syp[k] = py;  skp[k] = pk;

        // within(pick, my 4 modes): identical FP form to v10 (sqrtf, strict <)
        float dx0 = p0.x - px, dy0 = p0.y - py;
        float dx1 = p1.x - px, dy1 = p1.y - py;
        float dx2 = p2.x - px, dy2 = p2.y - py;
        float dx3 = p3.x - px, dy3 = p3.y - py;
        ls0 *= (sqrtf(dx0 * dx0 + dy0 * dy0) < thresh) ? 0.01f : 1.0f;
        ls1 *= (sqrtf(dx1 * dx1 + dy1 * dy1) < thresh) ? 0.01f : 1.0f;
        ls2 *= (sqrtf(dx2 * dx2 + dy2 * dy2) < thresh) ? 0.01f : 1.0f;
        ls3 *= (sqrtf(dx3 * dx3 + dy3 * dy3) < thresh) ? 0.01f : 1.0f;
        ls0 = (idx == o)      ? -1.0f : ls0;
        ls1 = (idx == o + 8)  ? -1.0f : ls1;
        ls2 = (idx == o + 16) ? -1.0f : ls2;
        ls3 = (idx == o + 24) ? -1.0f : ls3;
    }

    // ---- trajectory gather: per mode (literal), steps t=o and t=o+8 ----
    F3 ptA[KP], ptB[KP];
    #pragma unroll
    for (int m = 0; m < KP; ++m) {
        size_t row = ((size_t)sel[m] * NAG + a) * NSTEP;
        ptA[m] = *(const F3*)(tb + (row + (4 + 5 * o)) * 3);
        ptB[m] = *(const F3*)(tb + (row + (4 + 5 * (o + 8))) * 3);
    }

    // ---- MPA tail: redundant on all 8 lanes, registers only ----
    float ssum = 0.f;
    #pragma unroll
    for (int k = 0; k < KP; ++k) ssum += skp[k];
    float sk[KP], sk0[KP];
    #pragma unroll
    for (int k = 0; k < KP; ++k) { sk[k] = skp[k] / ssum; sk0[k] = sk[k]; }

    unsigned w2[KP];
    #pragma unroll
    for (int i = 0; i < KP; ++i) {
        unsigned r = 0;
        #pragma unroll
        for (int j = 0; j < KP; ++j) {
            float dx = sxp[i] - sxp[j], dy = syp[i] - syp[j];
            r |= (sqrtf(dx * dx + dy * dy) < thresh) ? (1u << j) : 0u;
        }
        w2[i] = r;
    }

    int rank[KP];
    #pragma unroll
    for (int j = 0; j < KP; ++j) {
        int r = 0;
        #pragma unroll
        for (int i = 0; i < KP; ++i)
            r += ((sk0[i] > sk0[j]) || (sk0[i] == sk0[j] && i < j)) ? 1 : 0;
        rank[j] = r;
    }

    #pragma unroll
    for (int t = 0; t < KP; ++t) {
        float sk_k = sk[0]; unsigned w2k = w2[0];
        #pragma unroll
        for (int j = 1; j < KP; ++j) {
            bool is = (rank[j] == t);
            sk_k = is ? sk[j] : sk_k;
            w2k  = is ? w2[j] : w2k;
        }
        bool any = false;
        #pragma unroll
        for (int j = 0; j < KP; ++j)
            any = any || ((((w2k >> j) & 1u) != 0u) && (sk[j] > sk_k));
        #pragma unroll
        for (int j = 0; j < KP; ++j)
            if (rank[j] == t && any) sk[j] = 0.001f;
    }

    float s2 = 0.f;
    #pragma unroll
    for (int k = 0; k < KP; ++k) s2 += sk[k];
    #pragma unroll
    for (int k = 0; k < KP; ++k) sk[k] /= s2;
    float q[KP]; float s3 = 0.f;
    #pragma unroll
    for (int k = 0; k < KP; ++k) { q[k] = sk[k] * sk[k]; s3 += q[k]; }

    // ---- score store: lanes 0-5 of each 8-group ----
    float qs = q[0] / s3;
    qs = (o == 1) ? q[1] / s3 : qs;
    qs = (o == 2) ? q[2] / s3 : qs;
    qs = (o == 3) ? q[3] / s3 : qs;
    qs = (o == 4) ? q[4] / s3 : qs;
    qs = (o == 5) ? q[5] / s3 : qs;
    const size_t SCBASE = (size_t)NSC * NAG * KP * TOUT * 3;
    if (o < KP) out[SCBASE + (size_t)ga * KP + o] = qs;

    // ---- trajectory stores: e = 16m + o and 16m + o + 8 ----
    size_t ob = (size_t)ga * (KP * TOUT * 3);
    #pragma unroll
    for (int m = 0; m < KP; ++m) {
        *(F3*)(out + ob + (size_t)(16 * m + o) * 3)     = ptA[m];
        *(F3*)(out + ob + (size_t)(16 * m + o + 8) * 3) = ptB[m];
    }
}

extern "C" void kernel_launch(void* const* d_in, const int* in_sizes, int n_in,
                              void* d_out, int out_size, void* d_ws, size_t ws_size,
                              hipStream_t stream) {
    const float* ag_type = (const float*)d_in[0];
    const float* trajs   = (const float*)d_in[1];
    const float* scores  = (const float*)d_in[2];
    float* out = (float*)d_out;

    womd_pp11<<<NSC * NAG / 8, 64, 0, stream>>>(ag_type, trajs, scores, out);
}

// Round 12
// 39.961 us; speedup vs baseline: 1.0633x; 1.0633x over previous
//
#include <hip/hip_runtime.h>

// WOMD post-processing v12: v10 base (measured best, 28.35 us, bit-exact),
// with the trajectory gather for pick k issued IMMEDIATELY inside NMS
// iteration k (overlapping each gather's memory latency with the remaining
// picks' shuffle chains), instead of one batch after the whole NMS.
// Everything else (FP order, tie-breaks, layout) is byte-identical to v10.

#define NSC 64
#define NAG 64
#define NJF 32
#define NSTEP 80
#define KP 6
#define TOUT 16

struct F3 { float x, y, z; };

__global__ __launch_bounds__(64)
void womd_pp12(const float* __restrict__ ag_type,
               const float* __restrict__ trajs,
               const float* __restrict__ scores,
               float* __restrict__ out)
{
    const int tid = threadIdx.x;
    const int g   = tid >> 4;              // group 0..3 = agent slot
    const int gl  = tid & 15;              // lane within group
    const int ga  = blockIdx.x * 4 + g;    // global agent 0..4095
    const int s   = ga >> 6;               // scene
    const int a   = ga & 63;               // agent

    // modes owned by this lane: j0 = gl, j1 = gl + 16
    // ---- loads ----
    const float* sp = scores + (size_t)s * NJF * NAG + a;
    float raw0 = sp[(size_t)gl * NAG];
    float raw1 = sp[(size_t)(gl + 16) * NAG];

    const float* tb = trajs + (size_t)s * NJF * NAG * NSTEP * 3;  // scene base
    size_t e0 = (((size_t)gl * NAG + a) * NSTEP + (NSTEP - 1)) * 3;
    size_t e1 = (((size_t)(gl + 16) * NAG + a) * NSTEP + (NSTEP - 1)) * 3;
    float2 p0 = *(const float2*)(tb + e0);     // endpoint of mode j0
    float2 p1 = *(const float2*)(tb + e1);     // endpoint of mode j1

    F3 atv = *(const F3*)(ag_type + (size_t)(s * NAG + a) * 3);
    const float thresh = atv.x * 2.5f + atv.y * 1.0f + atv.z * 2.0f;

    // ---- softmax over 32 modes (16-lane butterfly, 2 modes/lane) ----
    float mx = fmaxf(raw0, raw1);
    #pragma unroll
    for (int off = 8; off > 0; off >>= 1)
        mx = fmaxf(mx, __shfl_xor(mx, off, 16));
    float ev0 = expf(raw0 - mx);
    float ev1 = expf(raw1 - mx);
    float sum = ev0 + ev1;
    #pragma unroll
    for (int off = 8; off > 0; off >>= 1)
        sum += __shfl_xor(sum, off, 16);
    float sm0 = ev0 / sum;
    float sm1 = ev1 / sum;

    // ---- MTR NMS: 6 picks; gather load for pick k issued inside iteration k ----
    float skp[KP], sxp[KP], syp[KP];       // pick score/endpoint (all lanes)
    F3 pt[KP];                             // gathered trajectory points
    float ls0 = sm0, ls1 = sm1;
    #pragma unroll
    for (int k = 0; k < KP; ++k) {
        float v = fmaxf(ls0, ls1);
        #pragma unroll
        for (int off = 8; off > 0; off >>= 1)
            v = fmaxf(v, __shfl_xor(v, off, 16));
        // first mode index attaining the max (modes 0-15 before 16-31)
        unsigned long long b0 = __ballot(ls0 == v);
        unsigned long long b1 = __ballot(ls1 == v);
        unsigned m0 = (unsigned)(b0 >> (g * 16)) & 0xFFFFu;
        unsigned m1 = (unsigned)(b1 >> (g * 16)) & 0xFFFFu;
        int idx = m0 ? (__ffs(m0) - 1) : (16 + __ffs(m1) - 1);

        // >>> issue this pick's trajectory load NOW (latency hides under
        //     the remaining picks' shuffle chains) <<<
        size_t src = (((size_t)idx * NAG + a) * NSTEP + (4 + 5 * gl)) * 3;
        pt[k] = *(const F3*)(tb + src);

        // pick endpoint+score broadcast: source-side select, 3 shuffles
        int  il = idx & 15;
        bool lo = (idx < 16);
        float sxv = lo ? p0.x : p1.x;
        float syv = lo ? p0.y : p1.y;
        float skv = lo ? sm0 : sm1;
        float px = __shfl(sxv, il, 16);
        float py = __shfl(syv, il, 16);
        float pk = __shfl(skv, il, 16);
        sxp[k] = px;  syp[k] = py;  skp[k] = pk;

        // within(pick, my modes): identical FP to v10 (sqrtf, strict <)
        float dx0 = p0.x - px, dy0 = p0.y - py;
        float dx1 = p1.x - px, dy1 = p1.y - py;
        bool w0 = sqrtf(dx0 * dx0 + dy0 * dy0) < thresh;
        bool w1 = sqrtf(dx1 * dx1 + dy1 * dy1) < thresh;
        ls0 *= w0 ? 0.01f : 1.0f;          // 0.99f+0.01f == 1.0f
        ls1 *= w1 ? 0.01f : 1.0f;
        ls0 = (gl == idx)      ? -1.0f : ls0;
        ls1 = (gl + 16 == idx) ? -1.0f : ls1;
    }

    // ---- MPA tail: redundant on all 16 lanes, registers only ----
    float ssum = 0.f;
    #pragma unroll
    for (int k = 0; k < KP; ++k) ssum += skp[k];
    float sk[KP], sk0[KP];
    #pragma unroll
    for (int k = 0; k < KP; ++k) { sk[k] = skp[k] / ssum; sk0[k] = sk[k]; }

    unsigned w2[KP];
    #pragma unroll
    for (int i = 0; i < KP; ++i) {
        unsigned r = 0;
        #pragma unroll
        for (int j = 0; j < KP; ++j) {
            float dx = sxp[i] - sxp[j], dy = syp[i] - syp[j];
            r |= (sqrtf(dx * dx + dy * dy) < thresh) ? (1u << j) : 0u;
        }
        w2[i] = r;
    }

    // stable descending rank (ties -> lower index)
    int rank[KP];
    #pragma unroll
    for (int j = 0; j < KP; ++j) {
        int r = 0;
        #pragma unroll
        for (int i = 0; i < KP; ++i)
            r += ((sk0[i] > sk0[j]) || (sk0[i] == sk0[j] && i < j)) ? 1 : 0;
        rank[j] = r;
    }

    // sequential MPA scan in rank order (select chains, literal idx only)
    #pragma unroll
    for (int t = 0; t < KP; ++t) {
        float sk_k = sk[0]; unsigned w2k = w2[0];
        #pragma unroll
        for (int j = 1; j < KP; ++j) {
            bool is = (rank[j] == t);
            sk_k = is ? sk[j] : sk_k;
            w2k  = is ? w2[j] : w2k;
        }
        bool any = false;
        #pragma unroll
        for (int j = 0; j < KP; ++j)
            any = any || ((((w2k >> j) & 1u) != 0u) && (sk[j] > sk_k));
        #pragma unroll
        for (int j = 0; j < KP; ++j)
            if (rank[j] == t && any) sk[j] = 0.001f;
    }

    // normalize; softmax(log p / 0.5) == p^2 / sum(p^2)
    float s2 = 0.f;
    #pragma unroll
    for (int k = 0; k < KP; ++k) s2 += sk[k];
    #pragma unroll
    for (int k = 0; k < KP; ++k) sk[k] /= s2;
    float q[KP]; float s3 = 0.f;
    #pragma unroll
    for (int k = 0; k < KP; ++k) { q[k] = sk[k] * sk[k]; s3 += q[k]; }

    // ---- score store: lanes 0-5 of each group, select chain ----
    float qs = q[0] / s3;
    qs = (gl == 1) ? q[1] / s3 : qs;
    qs = (gl == 2) ? q[2] / s3 : qs;
    qs = (gl == 3) ? q[3] / s3 : qs;
    qs = (gl == 4) ? q[4] / s3 : qs;
    qs = (gl == 5) ? q[5] / s3 : qs;
    const size_t SCBASE = (size_t)NSC * NAG * KP * TOUT * 3;
    if (gl < KP) out[SCBASE + (size_t)ga * KP + gl] = qs;

    // ---- trajectory stores: e = 16*i + gl (mode i, step gl) ----
    size_t ob = (size_t)ga * (KP * TOUT * 3);
    #pragma unroll
    for (int i = 0; i < KP; ++i)
        *(F3*)(out + ob + (size_t)(16 * i + gl) * 3) = pt[i];
}

extern "C" void kernel_launch(void* const* d_in, const int* in_sizes, int n_in,
                              void* d_out, int out_size, void* d_ws, size_t ws_size,
                              hipStream_t stream) {
    const float* ag_type = (const float*)d_in[0];
    const float* trajs   = (const float*)d_in[1];
    const float* scores  = (const float*)d_in[2];
    float* out = (float*)d_out;

    womd_pp12<<<NSC * NAG / 4, 64, 0, stream>>>(ag_type, trajs, scores, out);
}